// Round 1
// baseline (227.224 us; speedup 1.0000x reference)
//
#include <hip/hip_runtime.h>
#include <hip/hip_bf16.h>
#include <stdint.h>

#define S_TOK 3072
#define E_DIM 1280
#define H_NUM 20
#define D_HEAD 64
#define NSEG 16

typedef __attribute__((ext_vector_type(8))) short short8;
typedef __attribute__((ext_vector_type(4))) float f32x4;

__device__ __forceinline__ unsigned short f2bf(float f){
  union { float f; unsigned int i; } u; u.f = f;
  unsigned int r = u.i + 0x7FFFu + ((u.i >> 16) & 1u);
  return (unsigned short)(r >> 16);
}

__device__ __forceinline__ void gload_lds16(const void* g, void* l){
  __builtin_amdgcn_global_load_lds((__attribute__((address_space(1))) void*)(g),
                                   (__attribute__((address_space(3))) void*)(l), 16, 0, 0);
}

// ---------------- f32 -> bf16 conversion ----------------
__global__ void cvt_bf16(const float* __restrict__ src, unsigned short* __restrict__ dst, int n4){
  int i = blockIdx.x * blockDim.x + threadIdx.x;
  if (i >= n4) return;
  float4 v = reinterpret_cast<const float4*>(src)[i];
  ushort4 o;
  o.x = f2bf(v.x); o.y = f2bf(v.y); o.z = f2bf(v.z); o.w = f2bf(v.w);
  reinterpret_cast<ushort4*>(dst)[i] = o;
}

// ---------------- GEMM: C = A[M,K] @ B[N,K]^T  (bf16 in, f32 acc) ----------------
// MODE 0: QKV fused (N = 3*E): scatter q/k/v bf16 [H][S][D], bias bq / none / bv
// MODE 1: out proj (N = E): f32 out [S][E] + bias bo
template<int MODE>
__global__ __launch_bounds__(256, 2) void gemm_bt(
    const unsigned short* __restrict__ A,
    const unsigned short* __restrict__ B,
    const float* __restrict__ bias0,
    const float* __restrict__ bias1,
    unsigned short* __restrict__ Oq,
    unsigned short* __restrict__ Ok,
    unsigned short* __restrict__ Ov,
    float* __restrict__ Of,
    int M, int N, int K)
{
  __shared__ __align__(16) unsigned short As[2][128*64];
  __shared__ __align__(16) unsigned short Bs[2][128*64];

  const int nbn = N >> 7;
  const int bm = blockIdx.x / nbn;
  const int bn = blockIdx.x % nbn;
  const int row0 = bm << 7;
  const int col0 = bn << 7;

  const int tid  = threadIdx.x;
  const int lane = tid & 63;
  const int wrow = ((tid >> 7) & 1) * 64;
  const int wcol = ((tid >> 6) & 1) * 64;

  const f32x4 fz = {0.f, 0.f, 0.f, 0.f};
  f32x4 acc[4][4];
#pragma unroll
  for (int m = 0; m < 4; ++m)
#pragma unroll
    for (int n = 0; n < 4; ++n) acc[m][n] = fz;

  // stage one 128x64 bf16 tile of A and B each; LDS linear dest, inverse-swizzled
  // global source (rule #21): phys slot (row,p) holds logical k-slot p^(row&7)
  auto stage = [&](int buf, int k0){
#pragma unroll
    for (int i = 0; i < 4; ++i){
      int s = i*256 + tid;
      int r = s >> 3, p = s & 7;
      int ks = p ^ (r & 7);
      gload_lds16(A + (size_t)(row0 + r)*K + k0 + ks*8, &As[buf][s*8]);
    }
#pragma unroll
    for (int i = 0; i < 4; ++i){
      int s = i*256 + tid;
      int r = s >> 3, p = s & 7;
      int ks = p ^ (r & 7);
      gload_lds16(B + (size_t)(col0 + r)*K + k0 + ks*8, &Bs[buf][s*8]);
    }
  };

  const int nk = K >> 6;
  stage(0, 0);
  __syncthreads();
  int cur = 0;
  for (int t = 0; t < nk; ++t){
    if (t + 1 < nk) stage(cur ^ 1, (t + 1) << 6);
    short8 af[2][4], bfr[2][4];
#pragma unroll
    for (int kk = 0; kk < 2; ++kk){
#pragma unroll
      for (int m = 0; m < 4; ++m){
        int ra = wrow + m*16 + (lane & 15);
        int slot = kk*4 + (lane >> 4);
        af[kk][m]  = *reinterpret_cast<const short8*>(&As[cur][ra*64 + ((slot ^ (ra & 7)))*8]);
        int rb = wcol + m*16 + (lane & 15);
        bfr[kk][m] = *reinterpret_cast<const short8*>(&Bs[cur][rb*64 + ((slot ^ (rb & 7)))*8]);
      }
    }
#pragma unroll
    for (int kk = 0; kk < 2; ++kk)
#pragma unroll
      for (int m = 0; m < 4; ++m)
#pragma unroll
        for (int n = 0; n < 4; ++n)
          acc[m][n] = __builtin_amdgcn_mfma_f32_16x16x32_bf16(af[kk][m], bfr[kk][n], acc[m][n], 0, 0, 0);
    __syncthreads();
    cur ^= 1;
  }

#pragma unroll
  for (int m = 0; m < 4; ++m){
#pragma unroll
    for (int n = 0; n < 4; ++n){
#pragma unroll
      for (int j = 0; j < 4; ++j){
        int r = row0 + wrow + m*16 + (lane >> 4)*4 + j;
        int c = col0 + wcol + n*16 + (lane & 15);
        float v = acc[m][n][j];
        if (MODE == 0){
          int mat = c / E_DIM;
          int cc  = c - mat * E_DIM;
          float b = (mat == 0) ? bias0[cc] : (mat == 2 ? bias1[cc] : 0.0f);
          unsigned short ov = f2bf(v + b);
          int hh = cc >> 6, dd = cc & 63;
          unsigned short* dst = (mat == 0) ? Oq : ((mat == 1) ? Ok : Ov);
          dst[((size_t)hh * S_TOK + r) * D_HEAD + dd] = ov;
        } else {
          Of[(size_t)r * E_DIM + c] = v + bias0[c];
        }
      }
    }
  }
}

// ---------------- block-diagonal attention ----------------
// grid = H*NSEG blocks, 384 threads (6 waves x 32 Q-rows). L <= 192.
__global__ __launch_bounds__(384, 1) void attn_kernel(
    const unsigned short* __restrict__ Q,
    const unsigned short* __restrict__ Kb,
    const unsigned short* __restrict__ V,
    const int* __restrict__ cu,
    unsigned short* __restrict__ O)
{
  __shared__ __align__(16) unsigned short Klds[192*64];   // swizzled [192][64]
  __shared__ __align__(16) unsigned short Vt[64*232];     // [d][s], padded
  __shared__ __align__(16) unsigned short P[192*208];     // swizzled rows

  const int bid = blockIdx.x;
  const int h   = bid >> 4;
  const int seg = bid & 15;
  const int s0  = cu[seg];
  const int L   = cu[seg + 1] - s0;
  if (L <= 0) return;

  const int tid  = threadIdx.x;
  const int lane = tid & 63;
  const int w    = tid >> 6;

  const unsigned short* qh = Q  + (size_t)h * S_TOK * D_HEAD;
  const unsigned short* kh = Kb + (size_t)h * S_TOK * D_HEAD;
  const unsigned short* vh = V  + (size_t)h * S_TOK * D_HEAD;

  // stage K swizzled via global_load_lds (1536 slots)
#pragma unroll
  for (int i = 0; i < 4; ++i){
    int s = i*384 + tid;
    int r = s >> 3, p = s & 7;
    int ks = p ^ (r & 7);
    int sr = s0 + (r < L ? r : L - 1);
    gload_lds16(kh + (size_t)sr*64 + ks*8, &Klds[s*8]);
  }
  // stage V transposed: Vt[d][s]
#pragma unroll
  for (int i = 0; i < 4; ++i){
    int e  = (i*384 + tid) * 8;
    int sr = e >> 6, d0 = e & 63;
    int svr = s0 + (sr < L ? sr : L - 1);
    short8 vv = *reinterpret_cast<const short8*>(vh + (size_t)svr*64 + d0);
#pragma unroll
    for (int j = 0; j < 8; ++j) Vt[(d0 + j)*232 + sr] = (unsigned short)vv[j];
  }

  // Q fragments direct from global (wave owns rows w*32 .. w*32+31)
  short8 qf[2][2];
#pragma unroll
  for (int mt = 0; mt < 2; ++mt)
#pragma unroll
    for (int kk = 0; kk < 2; ++kk){
      int r  = w*32 + mt*16 + (lane & 15);
      int sr = s0 + (r < L ? r : L - 1);
      qf[mt][kk] = *reinterpret_cast<const short8*>(qh + (size_t)sr*64 + kk*32 + (lane >> 4)*8);
    }

  __syncthreads();

  const f32x4 fz = {0.f, 0.f, 0.f, 0.f};
  f32x4 sacc[2][12];
#pragma unroll
  for (int mt = 0; mt < 2; ++mt)
#pragma unroll
    for (int nt = 0; nt < 12; ++nt) sacc[mt][nt] = fz;

#pragma unroll 4
  for (int nt = 0; nt < 12; ++nt){
    short8 kf[2];
#pragma unroll
    for (int kk = 0; kk < 2; ++kk){
      int rb = nt*16 + (lane & 15);
      int slot = kk*4 + (lane >> 4);
      kf[kk] = *reinterpret_cast<const short8*>(&Klds[rb*64 + ((slot ^ (rb & 7)))*8]);
    }
#pragma unroll
    for (int mt = 0; mt < 2; ++mt){
      sacc[mt][nt] = __builtin_amdgcn_mfma_f32_16x16x32_bf16(qf[mt][0], kf[0], sacc[mt][nt], 0, 0, 0);
      sacc[mt][nt] = __builtin_amdgcn_mfma_f32_16x16x32_bf16(qf[mt][1], kf[1], sacc[mt][nt], 0, 0, 0);
    }
  }

  // softmax over 192 cols (C layout: col=lane&15, row=(lane>>4)*4+j)
  const float SCL = 0.125f * 1.44269504088896f;  // /sqrt(64) then exp2
  float rinv[2][4];
#pragma unroll
  for (int mt = 0; mt < 2; ++mt){
#pragma unroll
    for (int j = 0; j < 4; ++j){
      float mx = -1e30f;
#pragma unroll
      for (int nt = 0; nt < 12; ++nt){
        int c = nt*16 + (lane & 15);
        float vv = (c < L) ? sacc[mt][nt][j] : -1e30f;
        sacc[mt][nt][j] = vv;
        mx = fmaxf(mx, vv);
      }
      mx = fmaxf(mx, __shfl_xor(mx, 1, 64));
      mx = fmaxf(mx, __shfl_xor(mx, 2, 64));
      mx = fmaxf(mx, __shfl_xor(mx, 4, 64));
      mx = fmaxf(mx, __shfl_xor(mx, 8, 64));
      float sum = 0.f;
#pragma unroll
      for (int nt = 0; nt < 12; ++nt){
        float pp = exp2f((sacc[mt][nt][j] - mx) * SCL);
        sacc[mt][nt][j] = pp;
        sum += pp;
      }
      sum += __shfl_xor(sum, 1, 64);
      sum += __shfl_xor(sum, 2, 64);
      sum += __shfl_xor(sum, 4, 64);
      sum += __shfl_xor(sum, 8, 64);
      rinv[mt][j] = 1.0f / sum;
    }
  }

  // P -> LDS bf16 (unnormalized), swizzled rows
#pragma unroll
  for (int mt = 0; mt < 2; ++mt)
#pragma unroll
    for (int nt = 0; nt < 12; ++nt)
#pragma unroll
      for (int j = 0; j < 4; ++j){
        int r = w*32 + mt*16 + (lane >> 4)*4 + j;
        int c = nt*16 + (lane & 15);
        int slot = c >> 3;
        int sl = (slot & ~7) | ((slot ^ r) & 7);
        P[r*208 + sl*8 + (c & 7)] = f2bf(sacc[mt][nt][j]);
      }
  __syncthreads();

  // O = P @ V
  f32x4 oacc[2][4];
#pragma unroll
  for (int mt = 0; mt < 2; ++mt)
#pragma unroll
    for (int nt = 0; nt < 4; ++nt) oacc[mt][nt] = fz;

#pragma unroll 2
  for (int kk = 0; kk < 6; ++kk){
    short8 pf[2];
#pragma unroll
    for (int mt = 0; mt < 2; ++mt){
      int r = w*32 + mt*16 + (lane & 15);
      int slot = kk*4 + (lane >> 4);
      int sl = (slot & ~7) | ((slot ^ r) & 7);
      pf[mt] = *reinterpret_cast<const short8*>(&P[r*208 + sl*8]);
    }
    short8 vf[4];
#pragma unroll
    for (int nt = 0; nt < 4; ++nt){
      int dcol = nt*16 + (lane & 15);
      vf[nt] = *reinterpret_cast<const short8*>(&Vt[dcol*232 + kk*32 + (lane >> 4)*8]);
    }
#pragma unroll
    for (int mt = 0; mt < 2; ++mt)
#pragma unroll
      for (int nt = 0; nt < 4; ++nt)
        oacc[mt][nt] = __builtin_amdgcn_mfma_f32_16x16x32_bf16(pf[mt], vf[nt], oacc[mt][nt], 0, 0, 0);
  }

  // store O (bf16 [S][E]) with row-sum normalization
#pragma unroll
  for (int mt = 0; mt < 2; ++mt)
#pragma unroll
    for (int nt = 0; nt < 4; ++nt)
#pragma unroll
      for (int j = 0; j < 4; ++j){
        int r = w*32 + mt*16 + (lane >> 4)*4 + j;
        if (r < L){
          int c = nt*16 + (lane & 15);
          O[(size_t)(s0 + r) * E_DIM + h*64 + c] = f2bf(oacc[mt][nt][j] * rinv[mt][j]);
        }
      }
}

// ---------------- host launch ----------------
extern "C" void kernel_launch(void* const* d_in, const int* in_sizes, int n_in,
                              void* d_out, int out_size, void* d_ws, size_t ws_size,
                              hipStream_t stream)
{
  const float* hs = (const float*)d_in[0];
  const float* Wq = (const float*)d_in[1];
  const float* bq = (const float*)d_in[2];
  const float* Wk = (const float*)d_in[3];
  const float* Wv = (const float*)d_in[4];
  const float* bv = (const float*)d_in[5];
  const float* Wo = (const float*)d_in[6];
  const float* bo = (const float*)d_in[7];
  const int*   cu = (const int*)d_in[8];
  float* out = (float*)d_out;

  unsigned short* p = (unsigned short*)d_ws;
  unsigned short* hsb  = p; p += (size_t)S_TOK * E_DIM;
  unsigned short* wqkv = p; p += (size_t)3 * E_DIM * E_DIM;
  unsigned short* wob  = p; p += (size_t)E_DIM * E_DIM;
  unsigned short* qb   = p; p += (size_t)S_TOK * E_DIM;
  unsigned short* kb   = p; p += (size_t)S_TOK * E_DIM;
  unsigned short* vb   = p; p += (size_t)S_TOK * E_DIM;
  unsigned short* aob  = p; p += (size_t)S_TOK * E_DIM;

  const int nHS = S_TOK * E_DIM / 4;
  const int nW  = E_DIM * E_DIM / 4;
  cvt_bf16<<<(nHS + 255) / 256, 256, 0, stream>>>(hs, hsb, nHS);
  cvt_bf16<<<(nW + 255) / 256, 256, 0, stream>>>(Wq, wqkv,                nW);
  cvt_bf16<<<(nW + 255) / 256, 256, 0, stream>>>(Wk, wqkv +     E_DIM*E_DIM, nW);
  cvt_bf16<<<(nW + 255) / 256, 256, 0, stream>>>(Wv, wqkv + 2 * E_DIM*E_DIM, nW);
  cvt_bf16<<<(nW + 255) / 256, 256, 0, stream>>>(Wo, wob,                 nW);

  // fused QKV projection: [3072, 3840] = hs @ [Wq;Wk;Wv]^T
  gemm_bt<0><<<(S_TOK/128) * (3*E_DIM/128), 256, 0, stream>>>(
      hsb, wqkv, bq, bv, qb, kb, vb, nullptr, S_TOK, 3*E_DIM, E_DIM);

  // block-diagonal attention
  attn_kernel<<<H_NUM * NSEG, 384, 0, stream>>>(qb, kb, vb, cu, aob);

  // output projection
  gemm_bt<1><<<(S_TOK/128) * (E_DIM/128), 256, 0, stream>>>(
      aob, wob, bo, nullptr, nullptr, nullptr, nullptr, out, S_TOK, E_DIM, E_DIM);
}

// Round 2
// 218.405 us; speedup vs baseline: 1.0404x; 1.0404x over previous
//
#include <hip/hip_runtime.h>
#include <hip/hip_bf16.h>
#include <stdint.h>

#define S_TOK 3072
#define E_DIM 1280
#define H_NUM 20
#define D_HEAD 64
#define NSEG 16

typedef __attribute__((ext_vector_type(8))) short short8;
typedef __attribute__((ext_vector_type(4))) float f32x4;

__device__ __forceinline__ unsigned short f2bf(float f){
  union { float f; unsigned int i; } u; u.f = f;
  unsigned int r = u.i + 0x7FFFu + ((u.i >> 16) & 1u);
  return (unsigned short)(r >> 16);
}

__device__ __forceinline__ void gload_lds16(const void* g, void* l){
  __builtin_amdgcn_global_load_lds((__attribute__((address_space(1))) void*)(g),
                                   (__attribute__((address_space(3))) void*)(l), 16, 0, 0);
}

// ---------------- f32 -> bf16 conversion ----------------
__global__ void cvt_bf16(const float* __restrict__ src, unsigned short* __restrict__ dst, int n4){
  int i = blockIdx.x * blockDim.x + threadIdx.x;
  if (i >= n4) return;
  float4 v = reinterpret_cast<const float4*>(src)[i];
  ushort4 o;
  o.x = f2bf(v.x); o.y = f2bf(v.y); o.z = f2bf(v.z); o.w = f2bf(v.w);
  reinterpret_cast<ushort4*>(dst)[i] = o;
}

// four E*E weights in one launch: Wq,Wk,Wv -> dqkv (contig), Wo -> dob
__global__ void cvt_w4(const float* __restrict__ w0, const float* __restrict__ w1,
                       const float* __restrict__ w2, const float* __restrict__ w3,
                       unsigned short* __restrict__ dqkv, unsigned short* __restrict__ dob,
                       int n4each){
  int i = blockIdx.x * blockDim.x + threadIdx.x;
  int w = i / n4each;
  int j = i - w * n4each;
  if (w >= 4) return;
  const float* src = (w == 0) ? w0 : (w == 1) ? w1 : (w == 2) ? w2 : w3;
  float4 v = reinterpret_cast<const float4*>(src)[j];
  ushort4 o;
  o.x = f2bf(v.x); o.y = f2bf(v.y); o.z = f2bf(v.z); o.w = f2bf(v.w);
  if (w < 3) reinterpret_cast<ushort4*>(dqkv)[(size_t)w * n4each + j] = o;
  else       reinterpret_cast<ushort4*>(dob)[j] = o;
}

// ---------------- GEMM: C = A[M,K] @ B[N,K]^T  (bf16 in, f32 acc) ----------------
template<int MODE>
__global__ __launch_bounds__(256, 2) void gemm_bt(
    const unsigned short* __restrict__ A,
    const unsigned short* __restrict__ B,
    const float* __restrict__ bias0,
    const float* __restrict__ bias1,
    unsigned short* __restrict__ Oq,
    unsigned short* __restrict__ Ok,
    unsigned short* __restrict__ Ov,
    float* __restrict__ Of,
    int M, int N, int K)
{
  __shared__ __align__(16) unsigned short As[2][128*64];
  __shared__ __align__(16) unsigned short Bs[2][128*64];

  const int nbn = N >> 7;
  const int bm = blockIdx.x / nbn;
  const int bn = blockIdx.x % nbn;
  const int row0 = bm << 7;
  const int col0 = bn << 7;

  const int tid  = threadIdx.x;
  const int lane = tid & 63;
  const int wrow = ((tid >> 7) & 1) * 64;
  const int wcol = ((tid >> 6) & 1) * 64;

  const f32x4 fz = {0.f, 0.f, 0.f, 0.f};
  f32x4 acc[4][4];
#pragma unroll
  for (int m = 0; m < 4; ++m)
#pragma unroll
    for (int n = 0; n < 4; ++n) acc[m][n] = fz;

  auto stage = [&](int buf, int k0){
#pragma unroll
    for (int i = 0; i < 4; ++i){
      int s = i*256 + tid;
      int r = s >> 3, p = s & 7;
      int ks = p ^ (r & 7);
      gload_lds16(A + (size_t)(row0 + r)*K + k0 + ks*8, &As[buf][s*8]);
    }
#pragma unroll
    for (int i = 0; i < 4; ++i){
      int s = i*256 + tid;
      int r = s >> 3, p = s & 7;
      int ks = p ^ (r & 7);
      gload_lds16(B + (size_t)(col0 + r)*K + k0 + ks*8, &Bs[buf][s*8]);
    }
  };

  const int nk = K >> 6;
  stage(0, 0);
  __syncthreads();
  int cur = 0;
  for (int t = 0; t < nk; ++t){
    if (t + 1 < nk) stage(cur ^ 1, (t + 1) << 6);
    short8 af[2][4], bfr[2][4];
#pragma unroll
    for (int kk = 0; kk < 2; ++kk){
#pragma unroll
      for (int m = 0; m < 4; ++m){
        int ra = wrow + m*16 + (lane & 15);
        int slot = kk*4 + (lane >> 4);
        af[kk][m]  = *reinterpret_cast<const short8*>(&As[cur][ra*64 + ((slot ^ (ra & 7)))*8]);
        int rb = wcol + m*16 + (lane & 15);
        bfr[kk][m] = *reinterpret_cast<const short8*>(&Bs[cur][rb*64 + ((slot ^ (rb & 7)))*8]);
      }
    }
#pragma unroll
    for (int kk = 0; kk < 2; ++kk)
#pragma unroll
      for (int m = 0; m < 4; ++m)
#pragma unroll
        for (int n = 0; n < 4; ++n)
          acc[m][n] = __builtin_amdgcn_mfma_f32_16x16x32_bf16(af[kk][m], bfr[kk][n], acc[m][n], 0, 0, 0);
    __syncthreads();
    cur ^= 1;
  }

#pragma unroll
  for (int m = 0; m < 4; ++m){
#pragma unroll
    for (int n = 0; n < 4; ++n){
#pragma unroll
      for (int j = 0; j < 4; ++j){
        int r = row0 + wrow + m*16 + (lane >> 4)*4 + j;
        int c = col0 + wcol + n*16 + (lane & 15);
        float v = acc[m][n][j];
        if (MODE == 0){
          int mat = c / E_DIM;
          int cc  = c - mat * E_DIM;
          float b = (mat == 0) ? bias0[cc] : (mat == 2 ? bias1[cc] : 0.0f);
          unsigned short ov = f2bf(v + b);
          int hh = cc >> 6, dd = cc & 63;
          unsigned short* dst = (mat == 0) ? Oq : ((mat == 1) ? Ok : Ov);
          dst[((size_t)hh * S_TOK + r) * D_HEAD + dd] = ov;
        } else {
          Of[(size_t)r * E_DIM + c] = v + bias0[c];
        }
      }
    }
  }
}

// ---------------- block-diagonal attention ----------------
// grid = H*NSEG blocks, 384 threads (6 waves x 32 Q-rows), two 16-row passes
// per wave to keep the score state at 48 VGPRs (no spill).
__global__ __launch_bounds__(384, 3) void attn_kernel(
    const unsigned short* __restrict__ Q,
    const unsigned short* __restrict__ Kb,
    const unsigned short* __restrict__ V,
    const int* __restrict__ cu,
    unsigned short* __restrict__ O)
{
  __shared__ __align__(16) unsigned short Klds[192*64];    // swizzled [192][64]
  __shared__ __align__(16) unsigned short Vt[64*232];      // [d][s], padded
  __shared__ __align__(16) unsigned short Pw[6][16][56];   // per-wave P k-slice

  const int bid = blockIdx.x;
  const int h   = bid >> 4;
  const int seg = bid & 15;
  const int s0  = cu[seg];
  const int L   = cu[seg + 1] - s0;
  if (L <= 0) return;

  const int tid  = threadIdx.x;
  const int lane = tid & 63;
  const int w    = tid >> 6;

  const unsigned short* qh = Q  + (size_t)h * S_TOK * D_HEAD;
  const unsigned short* kh = Kb + (size_t)h * S_TOK * D_HEAD;
  const unsigned short* vh = V  + (size_t)h * S_TOK * D_HEAD;

  // stage K swizzled via global_load_lds (1536 x 16B slots)
#pragma unroll
  for (int i = 0; i < 4; ++i){
    int s = i*384 + tid;
    int r = s >> 3, p = s & 7;
    int ks = p ^ (r & 7);
    int sr = s0 + (r < L ? r : L - 1);
    gload_lds16(kh + (size_t)sr*64 + ks*8, &Klds[s*8]);
  }
  // stage V transposed: Vt[d][s]
#pragma unroll
  for (int i = 0; i < 4; ++i){
    int e  = (i*384 + tid) * 8;
    int sr = e >> 6, d0 = e & 63;
    int svr = s0 + (sr < L ? sr : L - 1);
    short8 vv = *reinterpret_cast<const short8*>(vh + (size_t)svr*64 + d0);
#pragma unroll
    for (int j = 0; j < 8; ++j) Vt[(d0 + j)*232 + sr] = (unsigned short)vv[j];
  }

  // Q fragments direct from global
  short8 qf[2][2];
#pragma unroll
  for (int mt = 0; mt < 2; ++mt)
#pragma unroll
    for (int kk = 0; kk < 2; ++kk){
      int r  = w*32 + mt*16 + (lane & 15);
      int sr = s0 + (r < L ? r : L - 1);
      qf[mt][kk] = *reinterpret_cast<const short8*>(qh + (size_t)sr*64 + kk*32 + (lane >> 4)*8);
    }

  __syncthreads();

  const f32x4 fz = {0.f, 0.f, 0.f, 0.f};
  const float SCL = 0.125f * 1.44269504088896f;  // /sqrt(64), then exp2
  f32x4 oacc[2][4];
#pragma unroll
  for (int mt = 0; mt < 2; ++mt)
#pragma unroll
    for (int nt = 0; nt < 4; ++nt) oacc[mt][nt] = fz;
  float rinv[2][4];

#pragma unroll
  for (int mt = 0; mt < 2; ++mt){
    // ---- QK^T for this 16-row pass ----
    f32x4 sacc[12];
#pragma unroll
    for (int nt = 0; nt < 12; ++nt) sacc[nt] = fz;

#pragma unroll 4
    for (int nt = 0; nt < 12; ++nt){
      short8 kf[2];
#pragma unroll
      for (int kk = 0; kk < 2; ++kk){
        int rb = nt*16 + (lane & 15);
        int slot = kk*4 + (lane >> 4);
        kf[kk] = *reinterpret_cast<const short8*>(&Klds[rb*64 + ((slot ^ (rb & 7)))*8]);
      }
      sacc[nt] = __builtin_amdgcn_mfma_f32_16x16x32_bf16(qf[mt][0], kf[0], sacc[nt], 0, 0, 0);
      sacc[nt] = __builtin_amdgcn_mfma_f32_16x16x32_bf16(qf[mt][1], kf[1], sacc[nt], 0, 0, 0);
    }

    // ---- softmax over 192 cols (row = (lane>>4)*4+j, col = nt*16 + (lane&15)) ----
#pragma unroll
    for (int j = 0; j < 4; ++j){
      float mx = -1e30f;
#pragma unroll
      for (int nt = 0; nt < 12; ++nt){
        int c = nt*16 + (lane & 15);
        float vv = (c < L) ? sacc[nt][j] : -1e30f;
        sacc[nt][j] = vv;
        mx = fmaxf(mx, vv);
      }
      mx = fmaxf(mx, __shfl_xor(mx, 1, 64));
      mx = fmaxf(mx, __shfl_xor(mx, 2, 64));
      mx = fmaxf(mx, __shfl_xor(mx, 4, 64));
      mx = fmaxf(mx, __shfl_xor(mx, 8, 64));
      float sum = 0.f;
#pragma unroll
      for (int nt = 0; nt < 12; ++nt){
        float pp = exp2f((sacc[nt][j] - mx) * SCL);
        sacc[nt][j] = pp;
        sum += pp;
      }
      sum += __shfl_xor(sum, 1, 64);
      sum += __shfl_xor(sum, 2, 64);
      sum += __shfl_xor(sum, 4, 64);
      sum += __shfl_xor(sum, 8, 64);
      rinv[mt][j] = 1.0f / sum;
    }

    // ---- PV via wave-private LDS P-slices (no barriers) ----
#pragma unroll
    for (int kk = 0; kk < 6; ++kk){
#pragma unroll
      for (int ntl = 0; ntl < 2; ++ntl){
        int nt = kk*2 + ntl;
#pragma unroll
        for (int j = 0; j < 4; ++j){
          int r  = (lane >> 4)*4 + j;
          int lc = ntl*16 + (lane & 15);
          Pw[w][r][lc] = f2bf(sacc[nt][j]);
        }
      }
      short8 pf = *reinterpret_cast<const short8*>(&Pw[w][lane & 15][(lane >> 4)*8]);
      short8 vf[4];
#pragma unroll
      for (int nt4 = 0; nt4 < 4; ++nt4){
        int dcol = nt4*16 + (lane & 15);
        vf[nt4] = *reinterpret_cast<const short8*>(&Vt[dcol*232 + kk*32 + (lane >> 4)*8]);
      }
#pragma unroll
      for (int nt4 = 0; nt4 < 4; ++nt4)
        oacc[mt][nt4] = __builtin_amdgcn_mfma_f32_16x16x32_bf16(pf, vf[nt4], oacc[mt][nt4], 0, 0, 0);
    }
  }

  // ---- store O (bf16 [S][E]) with row-sum normalization ----
#pragma unroll
  for (int mt = 0; mt < 2; ++mt)
#pragma unroll
    for (int nt = 0; nt < 4; ++nt)
#pragma unroll
      for (int j = 0; j < 4; ++j){
        int r = w*32 + mt*16 + (lane >> 4)*4 + j;
        if (r < L){
          int c = nt*16 + (lane & 15);
          O[(size_t)(s0 + r) * E_DIM + h*64 + c] = f2bf(oacc[mt][nt][j] * rinv[mt][j]);
        }
      }
}

// ---------------- host launch ----------------
extern "C" void kernel_launch(void* const* d_in, const int* in_sizes, int n_in,
                              void* d_out, int out_size, void* d_ws, size_t ws_size,
                              hipStream_t stream)
{
  const float* hs = (const float*)d_in[0];
  const float* Wq = (const float*)d_in[1];
  const float* bq = (const float*)d_in[2];
  const float* Wk = (const float*)d_in[3];
  const float* Wv = (const float*)d_in[4];
  const float* bv = (const float*)d_in[5];
  const float* Wo = (const float*)d_in[6];
  const float* bo = (const float*)d_in[7];
  const int*   cu = (const int*)d_in[8];
  float* out = (float*)d_out;

  unsigned short* p = (unsigned short*)d_ws;
  unsigned short* hsb  = p; p += (size_t)S_TOK * E_DIM;
  unsigned short* wqkv = p; p += (size_t)3 * E_DIM * E_DIM;
  unsigned short* wob  = p; p += (size_t)E_DIM * E_DIM;
  unsigned short* qb   = p; p += (size_t)S_TOK * E_DIM;
  unsigned short* kb   = p; p += (size_t)S_TOK * E_DIM;
  unsigned short* vb   = p; p += (size_t)S_TOK * E_DIM;
  unsigned short* aob  = p; p += (size_t)S_TOK * E_DIM;

  const int nHS = S_TOK * E_DIM / 4;
  const int nW  = E_DIM * E_DIM / 4;
  cvt_bf16<<<(nHS + 255) / 256, 256, 0, stream>>>(hs, hsb, nHS);
  cvt_w4<<<(4 * nW + 255) / 256, 256, 0, stream>>>(Wq, Wk, Wv, Wo, wqkv, wob, nW);

  // fused QKV projection: [3072, 3840] = hs @ [Wq;Wk;Wv]^T
  gemm_bt<0><<<(S_TOK/128) * (3*E_DIM/128), 256, 0, stream>>>(
      hsb, wqkv, bq, bv, qb, kb, vb, nullptr, S_TOK, 3*E_DIM, E_DIM);

  // block-diagonal attention
  attn_kernel<<<H_NUM * NSEG, 384, 0, stream>>>(qb, kb, vb, cu, aob);

  // output projection
  gemm_bt<1><<<(S_TOK/128) * (E_DIM/128), 256, 0, stream>>>(
      aob, wob, bo, nullptr, nullptr, nullptr, nullptr, out, S_TOK, E_DIM, E_DIM);
}

// Round 3
// 132.109 us; speedup vs baseline: 1.7200x; 1.6532x over previous
//
#include <hip/hip_runtime.h>
#include <hip/hip_bf16.h>
#include <stdint.h>

#define S_TOK 3072
#define E_DIM 1280
#define H_NUM 20
#define D_HEAD 64
#define NSEG 16

typedef __attribute__((ext_vector_type(8))) short short8;
typedef __attribute__((ext_vector_type(4))) float f32x4;

__device__ __forceinline__ unsigned short f2bf(float f){
  union { float f; unsigned int i; } u; u.f = f;
  unsigned int r = u.i + 0x7FFFu + ((u.i >> 16) & 1u);
  return (unsigned short)(r >> 16);
}

__device__ __forceinline__ void gload_lds16(const void* g, void* l){
  __builtin_amdgcn_global_load_lds((__attribute__((address_space(1))) void*)(g),
                                   (__attribute__((address_space(3))) void*)(l), 16, 0, 0);
}

// ---------------- f32 -> bf16 conversion ----------------
__global__ void cvt_bf16(const float* __restrict__ src, unsigned short* __restrict__ dst, int n4){
  int i = blockIdx.x * blockDim.x + threadIdx.x;
  if (i >= n4) return;
  float4 v = reinterpret_cast<const float4*>(src)[i];
  ushort4 o;
  o.x = f2bf(v.x); o.y = f2bf(v.y); o.z = f2bf(v.z); o.w = f2bf(v.w);
  reinterpret_cast<ushort4*>(dst)[i] = o;
}

__global__ void cvt_w4(const float* __restrict__ w0, const float* __restrict__ w1,
                       const float* __restrict__ w2, const float* __restrict__ w3,
                       unsigned short* __restrict__ dqkv, unsigned short* __restrict__ dob,
                       int n4each){
  int i = blockIdx.x * blockDim.x + threadIdx.x;
  int w = i / n4each;
  int j = i - w * n4each;
  if (w >= 4) return;
  const float* src = (w == 0) ? w0 : (w == 1) ? w1 : (w == 2) ? w2 : w3;
  float4 v = reinterpret_cast<const float4*>(src)[j];
  ushort4 o;
  o.x = f2bf(v.x); o.y = f2bf(v.y); o.z = f2bf(v.z); o.w = f2bf(v.w);
  if (w < 3) reinterpret_cast<ushort4*>(dqkv)[(size_t)w * n4each + j] = o;
  else       reinterpret_cast<ushort4*>(dob)[j] = o;
}

// ---------------- GEMM: C = A[M,K] @ B[N,K]^T  (bf16 in, f32 acc) ----------------
// MODE 0: QKV fused (N=3E): LDS-staged epilogue, bf16 scatter to q/k/v [H][S][D]
// MODE 1: out proj (N=E): f32 out [S][E] + bias
template<int MODE>
__global__ __launch_bounds__(256, 2) void gemm_bt(
    const unsigned short* __restrict__ A,
    const unsigned short* __restrict__ B,
    const float* __restrict__ bias0,
    const float* __restrict__ bias1,
    unsigned short* __restrict__ Oq,
    unsigned short* __restrict__ Ok,
    unsigned short* __restrict__ Ov,
    float* __restrict__ Of,
    int M, int N, int K)
{
  __shared__ __align__(16) unsigned short As[2][128*64];
  __shared__ __align__(16) unsigned short Bs[2][128*64];

  const int nbn = N >> 7;
  const int bm = blockIdx.x / nbn;
  const int bn = blockIdx.x % nbn;
  const int row0 = bm << 7;
  const int col0 = bn << 7;

  const int tid  = threadIdx.x;
  const int lane = tid & 63;
  const int wrow = ((tid >> 7) & 1) * 64;
  const int wcol = ((tid >> 6) & 1) * 64;

  const f32x4 fz = {0.f, 0.f, 0.f, 0.f};
  f32x4 acc[4][4];
#pragma unroll
  for (int m = 0; m < 4; ++m)
#pragma unroll
    for (int n = 0; n < 4; ++n) acc[m][n] = fz;

  auto stage = [&](int buf, int k0){
#pragma unroll
    for (int i = 0; i < 4; ++i){
      int s = i*256 + tid;
      int r = s >> 3, p = s & 7;
      int ks = p ^ (r & 7);
      gload_lds16(A + (size_t)(row0 + r)*K + k0 + ks*8, &As[buf][s*8]);
    }
#pragma unroll
    for (int i = 0; i < 4; ++i){
      int s = i*256 + tid;
      int r = s >> 3, p = s & 7;
      int ks = p ^ (r & 7);
      gload_lds16(B + (size_t)(col0 + r)*K + k0 + ks*8, &Bs[buf][s*8]);
    }
  };

  const int nk = K >> 6;
  stage(0, 0);
  __syncthreads();
  int cur = 0;
  for (int t = 0; t < nk; ++t){
    if (t + 1 < nk) stage(cur ^ 1, (t + 1) << 6);
    short8 af[2][4], bfr[2][4];
#pragma unroll
    for (int kk = 0; kk < 2; ++kk){
#pragma unroll
      for (int m = 0; m < 4; ++m){
        int ra = wrow + m*16 + (lane & 15);
        int slot = kk*4 + (lane >> 4);
        af[kk][m]  = *reinterpret_cast<const short8*>(&As[cur][ra*64 + ((slot ^ (ra & 7)))*8]);
        int rb = wcol + m*16 + (lane & 15);
        bfr[kk][m] = *reinterpret_cast<const short8*>(&Bs[cur][rb*64 + ((slot ^ (rb & 7)))*8]);
      }
    }
#pragma unroll
    for (int kk = 0; kk < 2; ++kk)
#pragma unroll
      for (int m = 0; m < 4; ++m)
#pragma unroll
        for (int n = 0; n < 4; ++n)
          acc[m][n] = __builtin_amdgcn_mfma_f32_16x16x32_bf16(af[kk][m], bfr[kk][n], acc[m][n], 0, 0, 0);
    __syncthreads();
    cur ^= 1;
  }

  if (MODE == 0){
    // LDS-staged coalesced epilogue, two 64-row phases reusing As (16384 shorts)
    unsigned short* Cs = &As[0][0];
    const int CSTR = 136;                  // 64 x 136 = 8704 shorts
    const int mat = col0 / E_DIM;          // 1280 % 128 == 0: tile-uniform
    const int cc0 = col0 - mat * E_DIM;
    unsigned short* dst = (mat == 0) ? Oq : ((mat == 1) ? Ok : Ov);
#pragma unroll
    for (int ph = 0; ph < 2; ++ph){
      if (wrow == ph*64){
#pragma unroll
        for (int m = 0; m < 4; ++m)
#pragma unroll
          for (int n = 0; n < 4; ++n)
#pragma unroll
            for (int j = 0; j < 4; ++j){
              int r2 = m*16 + (lane >> 4)*4 + j;          // 0..63
              int c  = wcol + n*16 + (lane & 15);         // 0..127
              int cc = cc0 + c;
              float b = (mat == 0) ? bias0[cc] : (mat == 2 ? bias1[cc] : 0.0f);
              Cs[r2*CSTR + c] = f2bf(acc[m][n][j] + b);
            }
      }
      __syncthreads();
      {
        int r = tid >> 2, q = tid & 3;
        int gr = row0 + ph*64 + r;
#pragma unroll
        for (int i = 0; i < 4; ++i){
          int c = q*32 + i*8;
          short8 vv = *reinterpret_cast<const short8*>(&Cs[r*CSTR + c]);
          int cc = cc0 + c;
          int hh = cc >> 6, dd = cc & 63;
          *reinterpret_cast<short8*>(&dst[((size_t)hh * S_TOK + gr) * D_HEAD + dd]) = vv;
        }
      }
      __syncthreads();
    }
  } else {
#pragma unroll
    for (int m = 0; m < 4; ++m)
#pragma unroll
      for (int n = 0; n < 4; ++n)
#pragma unroll
        for (int j = 0; j < 4; ++j){
          int r = row0 + wrow + m*16 + (lane >> 4)*4 + j;
          int c = col0 + wcol + n*16 + (lane & 15);
          Of[(size_t)r * E_DIM + c] = acc[m][n][j] + bias0[c];
        }
  }
}

// ---------------- block-diagonal attention ----------------
// grid = H*NSEG*3 blocks of 256 threads (4 waves x 16 Q-rows = 64 rows/block).
// K fragments read directly from global (L1/L2); V transposed in LDS; per-wave
// P slices; LDS-staged coalesced O store.
#define VSTR 200
#define PSTR 72
__global__ __launch_bounds__(256, 3) void attn_kernel(
    const unsigned short* __restrict__ Q,
    const unsigned short* __restrict__ Kb,
    const unsigned short* __restrict__ V,
    const int* __restrict__ cu,
    unsigned short* __restrict__ O)
{
  __shared__ __align__(16) unsigned short Vt[64*VSTR];     // [d][k-row]
  __shared__ __align__(16) unsigned short Pw[4][16][PSTR]; // per-wave scratch

  const int bid  = blockIdx.x;
  const int unit = bid / 3;
  const int third= bid - unit*3;
  const int h    = unit >> 4;
  const int seg  = unit & 15;
  const int s0   = cu[seg];
  const int L    = cu[seg + 1] - s0;
  if (L <= 0) return;

  const int tid  = threadIdx.x;
  const int lane = tid & 63;
  const int w    = tid >> 6;
  const int row0g = third*64 + w*16;      // this wave's first q-row (segment-local)

  const unsigned short* qh = Q  + (size_t)h * S_TOK * D_HEAD;
  const unsigned short* kh = Kb + (size_t)h * S_TOK * D_HEAD;
  const unsigned short* vh = V  + (size_t)h * S_TOK * D_HEAD;

  // ---- stage V transposed: Vt[d][k]; lane-consecutive LDS writes ----
#pragma unroll
  for (int i = 0; i < 6; ++i){
    int task = i*256 + tid;            // 1536 tasks = 192 rows x 8 d-groups
    int sr   = task % 192;
    int grp  = task / 192;             // d-group: d = grp*8 .. grp*8+7
    int svr  = s0 + (sr < L ? sr : L - 1);
    short8 vv = *reinterpret_cast<const short8*>(vh + (size_t)svr*64 + grp*8);
#pragma unroll
    for (int j = 0; j < 8; ++j) Vt[(grp*8 + j)*VSTR + sr] = (unsigned short)vv[j];
  }

  // ---- Q fragments direct from global ----
  short8 qf[2];
#pragma unroll
  for (int kk = 0; kk < 2; ++kk){
    int r  = row0g + (lane & 15);
    int sr = s0 + (r < L ? r : L - 1);
    qf[kk] = *reinterpret_cast<const short8*>(qh + (size_t)sr*64 + kk*32 + (lane >> 4)*8);
  }

  __syncthreads();

  const f32x4 fz = {0.f, 0.f, 0.f, 0.f};
  const float SCL = 0.125f * 1.44269504088896f;  // /sqrt(64), then exp2

  // ---- QK^T: K fragments direct from global (L1/L2 resident) ----
  f32x4 sacc[12];
#pragma unroll
  for (int nt = 0; nt < 12; ++nt) sacc[nt] = fz;

#pragma unroll
  for (int nt = 0; nt < 12; ++nt){
    int rb = nt*16 + (lane & 15);
    int sr = s0 + (rb < L ? rb : L - 1);
    const unsigned short* kr = kh + (size_t)sr*64 + (lane >> 4)*8;
    short8 kf0 = *reinterpret_cast<const short8*>(kr);
    short8 kf1 = *reinterpret_cast<const short8*>(kr + 32);
    sacc[nt] = __builtin_amdgcn_mfma_f32_16x16x32_bf16(qf[0], kf0, sacc[nt], 0, 0, 0);
    sacc[nt] = __builtin_amdgcn_mfma_f32_16x16x32_bf16(qf[1], kf1, sacc[nt], 0, 0, 0);
  }

  // ---- softmax over 192 cols (row=(lane>>4)*4+j, col=nt*16+(lane&15)) ----
  float rinv[4];
#pragma unroll
  for (int j = 0; j < 4; ++j){
    float mx = -1e30f;
#pragma unroll
    for (int nt = 0; nt < 12; ++nt){
      int c = nt*16 + (lane & 15);
      float vv = (c < L) ? sacc[nt][j] : -1e30f;
      sacc[nt][j] = vv;
      mx = fmaxf(mx, vv);
    }
    mx = fmaxf(mx, __shfl_xor(mx, 1, 64));
    mx = fmaxf(mx, __shfl_xor(mx, 2, 64));
    mx = fmaxf(mx, __shfl_xor(mx, 4, 64));
    mx = fmaxf(mx, __shfl_xor(mx, 8, 64));
    float sum = 0.f;
#pragma unroll
    for (int nt = 0; nt < 12; ++nt){
      float pp = exp2f((sacc[nt][j] - mx) * SCL);
      sacc[nt][j] = pp;
      sum += pp;
    }
    sum += __shfl_xor(sum, 1, 64);
    sum += __shfl_xor(sum, 2, 64);
    sum += __shfl_xor(sum, 4, 64);
    sum += __shfl_xor(sum, 8, 64);
    rinv[j] = 1.0f / sum;
  }

  // ---- PV via wave-private LDS P-slices ----
  f32x4 oacc[4];
#pragma unroll
  for (int nt = 0; nt < 4; ++nt) oacc[nt] = fz;

#pragma unroll
  for (int kk = 0; kk < 6; ++kk){
#pragma unroll
    for (int ntl = 0; ntl < 2; ++ntl){
      int nt = kk*2 + ntl;
#pragma unroll
      for (int j = 0; j < 4; ++j)
        Pw[w][(lane >> 4)*4 + j][ntl*16 + (lane & 15)] = f2bf(sacc[nt][j]);
    }
    short8 pf = *reinterpret_cast<const short8*>(&Pw[w][lane & 15][(lane >> 4)*8]);
#pragma unroll
    for (int nt4 = 0; nt4 < 4; ++nt4){
      int dcol = nt4*16 + (lane & 15);
      short8 vf = *reinterpret_cast<const short8*>(&Vt[dcol*VSTR + kk*32 + (lane >> 4)*8]);
      oacc[nt4] = __builtin_amdgcn_mfma_f32_16x16x32_bf16(pf, vf, oacc[nt4], 0, 0, 0);
    }
  }

  // ---- normalize, stage in LDS, coalesced 16B store ----
#pragma unroll
  for (int nt4 = 0; nt4 < 4; ++nt4)
#pragma unroll
    for (int j = 0; j < 4; ++j)
      Pw[w][(lane >> 4)*4 + j][nt4*16 + (lane & 15)] = f2bf(oacc[nt4][j] * rinv[j]);

  {
    int r = lane >> 2;                 // 0..15
    int gr = row0g + r;
    if (gr < L){
#pragma unroll
      for (int part = 0; part < 2; ++part){
        int c0 = (lane & 3)*16 + part*8;
        short8 vv = *reinterpret_cast<const short8*>(&Pw[w][r][c0]);
        *reinterpret_cast<short8*>(&O[(size_t)(s0 + gr) * E_DIM + h*64 + c0]) = vv;
      }
    }
  }
}

// ---------------- host launch ----------------
extern "C" void kernel_launch(void* const* d_in, const int* in_sizes, int n_in,
                              void* d_out, int out_size, void* d_ws, size_t ws_size,
                              hipStream_t stream)
{
  const float* hs = (const float*)d_in[0];
  const float* Wq = (const float*)d_in[1];
  const float* bq = (const float*)d_in[2];
  const float* Wk = (const float*)d_in[3];
  const float* Wv = (const float*)d_in[4];
  const float* bv = (const float*)d_in[5];
  const float* Wo = (const float*)d_in[6];
  const float* bo = (const float*)d_in[7];
  const int*   cu = (const int*)d_in[8];
  float* out = (float*)d_out;

  unsigned short* p = (unsigned short*)d_ws;
  unsigned short* hsb  = p; p += (size_t)S_TOK * E_DIM;
  unsigned short* wqkv = p; p += (size_t)3 * E_DIM * E_DIM;
  unsigned short* wob  = p; p += (size_t)E_DIM * E_DIM;
  unsigned short* qb   = p; p += (size_t)S_TOK * E_DIM;
  unsigned short* kb   = p; p += (size_t)S_TOK * E_DIM;
  unsigned short* vb   = p; p += (size_t)S_TOK * E_DIM;
  unsigned short* aob  = p; p += (size_t)S_TOK * E_DIM;

  const int nHS = S_TOK * E_DIM / 4;
  const int nW  = E_DIM * E_DIM / 4;
  cvt_bf16<<<(nHS + 255) / 256, 256, 0, stream>>>(hs, hsb, nHS);
  cvt_w4<<<(4 * nW + 255) / 256, 256, 0, stream>>>(Wq, Wk, Wv, Wo, wqkv, wob, nW);

  gemm_bt<0><<<(S_TOK/128) * (3*E_DIM/128), 256, 0, stream>>>(
      hsb, wqkv, bq, bv, qb, kb, vb, nullptr, S_TOK, 3*E_DIM, E_DIM);

  attn_kernel<<<H_NUM * NSEG * 3, 256, 0, stream>>>(qb, kb, vb, cu, aob);

  gemm_bt<1><<<(S_TOK/128) * (E_DIM/128), 256, 0, stream>>>(
      aob, wob, bo, nullptr, nullptr, nullptr, nullptr, out, S_TOK, E_DIM, E_DIM);
}

// Round 4
// 116.323 us; speedup vs baseline: 1.9534x; 1.1357x over previous
//
#include <hip/hip_runtime.h>
#include <hip/hip_bf16.h>
#include <stdint.h>

#define S_TOK 3072
#define E_DIM 1280
#define H_NUM 20
#define D_HEAD 64
#define NSEG 16

typedef __attribute__((ext_vector_type(8))) short short8;
typedef __attribute__((ext_vector_type(4))) float f32x4;

__device__ __forceinline__ unsigned short f2bf(float f){
  union { float f; unsigned int i; } u; u.f = f;
  unsigned int r = u.i + 0x7FFFu + ((u.i >> 16) & 1u);
  return (unsigned short)(r >> 16);
}

__device__ __forceinline__ void gload_lds16(const void* g, void* l){
  __builtin_amdgcn_global_load_lds((__attribute__((address_space(1))) void*)(g),
                                   (__attribute__((address_space(3))) void*)(l), 16, 0, 0);
}

// ---------------- all f32 -> bf16 conversions in one launch ----------------
__global__ void cvt_all(const float* __restrict__ hs,
                        const float* __restrict__ w0, const float* __restrict__ w1,
                        const float* __restrict__ w2, const float* __restrict__ w3,
                        unsigned short* __restrict__ hsb,
                        unsigned short* __restrict__ dqkv, unsigned short* __restrict__ dob,
                        int nHS4, int nW4){
  int i = blockIdx.x * blockDim.x + threadIdx.x;
  const float* src;
  unsigned short* dst;
  size_t sj, dj;
  if (i < nHS4){
    src = hs; dst = hsb; sj = i; dj = i;
  } else {
    int t = i - nHS4;
    int w = t / nW4;
    if (w >= 4) return;
    int j = t - w * nW4;
    src = (w == 0) ? w0 : (w == 1) ? w1 : (w == 2) ? w2 : w3;
    sj = j;
    if (w < 3){ dst = dqkv; dj = (size_t)w * nW4 + j; }
    else      { dst = dob;  dj = j; }
  }
  float4 v = reinterpret_cast<const float4*>(src)[sj];
  ushort4 o;
  o.x = f2bf(v.x); o.y = f2bf(v.y); o.z = f2bf(v.z); o.w = f2bf(v.w);
  reinterpret_cast<ushort4*>(dst)[dj] = o;
}

// ---------------- GEMM: C = A[M,K] @ B[N,K]^T  (bf16 in, f32 acc) ----------------
// 128x128 tile, BK=32, double-buffered in ONE 32 KB LDS buffer -> 4 blocks/CU.
// MODE 0: QKV fused (N=3E): LDS-staged epilogue, bf16 scatter to q/k/v [H][S][D]
// MODE 1: out proj (N=E): f32 out [S][E] + bias
template<int MODE>
__global__ __launch_bounds__(256, 4) void gemm_bt(
    const unsigned short* __restrict__ A,
    const unsigned short* __restrict__ B,
    const float* __restrict__ bias0,
    const float* __restrict__ bias1,
    unsigned short* __restrict__ Oq,
    unsigned short* __restrict__ Ok,
    unsigned short* __restrict__ Ov,
    float* __restrict__ Of,
    int M, int N, int K)
{
  // [As0 | As1 | Bs0 | Bs1], each 128x32 shorts (4096)
  __shared__ __align__(16) unsigned short SH[16384];

  const int nbn = N >> 7;
  const int bm = blockIdx.x / nbn;
  const int bn = blockIdx.x % nbn;
  const int row0 = bm << 7;
  const int col0 = bn << 7;

  const int tid  = threadIdx.x;
  const int lane = tid & 63;
  const int wrow = ((tid >> 7) & 1) * 64;
  const int wcol = ((tid >> 6) & 1) * 64;

  const f32x4 fz = {0.f, 0.f, 0.f, 0.f};
  f32x4 acc[4][4];
#pragma unroll
  for (int m = 0; m < 4; ++m)
#pragma unroll
    for (int n = 0; n < 4; ++n) acc[m][n] = fz;

  // stage 128x32 bf16 tiles; linear LDS dest, inverse-swizzled global source
  auto stage = [&](int buf, int k0){
    unsigned short* As = SH + buf * 4096;
    unsigned short* Bs = SH + 8192 + buf * 4096;
#pragma unroll
    for (int i = 0; i < 2; ++i){
      int s = i*256 + tid;         // 0..511 (16B slots)
      int r = s >> 2, p = s & 3;
      int ks = p ^ (r & 3);
      gload_lds16(A + (size_t)(row0 + r)*K + k0 + ks*8, &As[s*8]);
    }
#pragma unroll
    for (int i = 0; i < 2; ++i){
      int s = i*256 + tid;
      int r = s >> 2, p = s & 3;
      int ks = p ^ (r & 3);
      gload_lds16(B + (size_t)(col0 + r)*K + k0 + ks*8, &Bs[s*8]);
    }
  };

  const int nk = K >> 5;
  stage(0, 0);
  __syncthreads();
  int cur = 0;
  for (int t = 0; t < nk; ++t){
    if (t + 1 < nk) stage(cur ^ 1, (t + 1) << 5);
    const unsigned short* As = SH + cur * 4096;
    const unsigned short* Bs = SH + 8192 + cur * 4096;
    short8 af[4], bfr[4];
#pragma unroll
    for (int m = 0; m < 4; ++m){
      int ra = wrow + m*16 + (lane & 15);
      int slot = lane >> 4;
      af[m]  = *reinterpret_cast<const short8*>(&As[ra*32 + ((slot ^ (ra & 3)))*8]);
      int rb = wcol + m*16 + (lane & 15);
      bfr[m] = *reinterpret_cast<const short8*>(&Bs[rb*32 + ((slot ^ (rb & 3)))*8]);
    }
#pragma unroll
    for (int m = 0; m < 4; ++m)
#pragma unroll
      for (int n = 0; n < 4; ++n)
        acc[m][n] = __builtin_amdgcn_mfma_f32_16x16x32_bf16(af[m], bfr[n], acc[m][n], 0, 0, 0);
    __syncthreads();
    cur ^= 1;
  }

  if (MODE == 0){
    // LDS-staged coalesced epilogue, two 64-row phases; Cs aliases the whole SH
    unsigned short* Cs = SH;
    const int CSTR = 136;                  // 64 x 136 = 8704 shorts <= 16384
    const int mat = col0 / E_DIM;          // tile-uniform (1280 % 128 == 0)
    const int cc0 = col0 - mat * E_DIM;
    unsigned short* dst = (mat == 0) ? Oq : ((mat == 1) ? Ok : Ov);
#pragma unroll
    for (int ph = 0; ph < 2; ++ph){
      if (wrow == ph*64){
#pragma unroll
        for (int m = 0; m < 4; ++m)
#pragma unroll
          for (int n = 0; n < 4; ++n)
#pragma unroll
            for (int j = 0; j < 4; ++j){
              int r2 = m*16 + (lane >> 4)*4 + j;          // 0..63
              int c  = wcol + n*16 + (lane & 15);         // 0..127
              int cc = cc0 + c;
              float b = (mat == 0) ? bias0[cc] : (mat == 2 ? bias1[cc] : 0.0f);
              Cs[r2*CSTR + c] = f2bf(acc[m][n][j] + b);
            }
      }
      __syncthreads();
      {
        int r = tid >> 2, q = tid & 3;
        int gr = row0 + ph*64 + r;
#pragma unroll
        for (int i = 0; i < 4; ++i){
          int c = q*32 + i*8;
          short8 vv = *reinterpret_cast<const short8*>(&Cs[r*CSTR + c]);
          int cc = cc0 + c;
          int hh = cc >> 6, dd = cc & 63;
          *reinterpret_cast<short8*>(&dst[((size_t)hh * S_TOK + gr) * D_HEAD + dd]) = vv;
        }
      }
      __syncthreads();
    }
  } else {
#pragma unroll
    for (int m = 0; m < 4; ++m)
#pragma unroll
      for (int n = 0; n < 4; ++n)
#pragma unroll
        for (int j = 0; j < 4; ++j){
          int r = row0 + wrow + m*16 + (lane >> 4)*4 + j;
          int c = col0 + wcol + n*16 + (lane & 15);
          Of[(size_t)r * E_DIM + c] = acc[m][n][j] + bias0[c];
        }
  }
}

// ---------------- block-diagonal attention ----------------
// grid = H*NSEG*3 blocks of 256 threads (4 waves x 16 Q-rows = 64 rows/block).
#define VSTR 200
#define PSTR 72
__global__ __launch_bounds__(256, 3) void attn_kernel(
    const unsigned short* __restrict__ Q,
    const unsigned short* __restrict__ Kb,
    const unsigned short* __restrict__ V,
    const int* __restrict__ cu,
    unsigned short* __restrict__ O)
{
  __shared__ __align__(16) unsigned short Vt[64*VSTR];     // [d][k-row]
  __shared__ __align__(16) unsigned short Pw[4][16][PSTR]; // per-wave scratch

  const int bid  = blockIdx.x;
  const int unit = bid / 3;
  const int third= bid - unit*3;
  const int h    = unit >> 4;
  const int seg  = unit & 15;
  const int s0   = cu[seg];
  const int L    = cu[seg + 1] - s0;
  if (L <= 0) return;

  const int tid  = threadIdx.x;
  const int lane = tid & 63;
  const int w    = tid >> 6;
  const int row0g = third*64 + w*16;

  const unsigned short* qh = Q  + (size_t)h * S_TOK * D_HEAD;
  const unsigned short* kh = Kb + (size_t)h * S_TOK * D_HEAD;
  const unsigned short* vh = V  + (size_t)h * S_TOK * D_HEAD;

#pragma unroll
  for (int i = 0; i < 6; ++i){
    int task = i*256 + tid;            // 1536 tasks = 192 rows x 8 d-groups
    int sr   = task % 192;
    int grp  = task / 192;
    int svr  = s0 + (sr < L ? sr : L - 1);
    short8 vv = *reinterpret_cast<const short8*>(vh + (size_t)svr*64 + grp*8);
#pragma unroll
    for (int j = 0; j < 8; ++j) Vt[(grp*8 + j)*VSTR + sr] = (unsigned short)vv[j];
  }

  short8 qf[2];
#pragma unroll
  for (int kk = 0; kk < 2; ++kk){
    int r  = row0g + (lane & 15);
    int sr = s0 + (r < L ? r : L - 1);
    qf[kk] = *reinterpret_cast<const short8*>(qh + (size_t)sr*64 + kk*32 + (lane >> 4)*8);
  }

  __syncthreads();

  const f32x4 fz = {0.f, 0.f, 0.f, 0.f};
  const float SCL = 0.125f * 1.44269504088896f;

  f32x4 sacc[12];
#pragma unroll
  for (int nt = 0; nt < 12; ++nt) sacc[nt] = fz;

#pragma unroll
  for (int nt = 0; nt < 12; ++nt){
    int rb = nt*16 + (lane & 15);
    int sr = s0 + (rb < L ? rb : L - 1);
    const unsigned short* kr = kh + (size_t)sr*64 + (lane >> 4)*8;
    short8 kf0 = *reinterpret_cast<const short8*>(kr);
    short8 kf1 = *reinterpret_cast<const short8*>(kr + 32);
    sacc[nt] = __builtin_amdgcn_mfma_f32_16x16x32_bf16(qf[0], kf0, sacc[nt], 0, 0, 0);
    sacc[nt] = __builtin_amdgcn_mfma_f32_16x16x32_bf16(qf[1], kf1, sacc[nt], 0, 0, 0);
  }

  float rinv[4];
#pragma unroll
  for (int j = 0; j < 4; ++j){
    float mx = -1e30f;
#pragma unroll
    for (int nt = 0; nt < 12; ++nt){
      int c = nt*16 + (lane & 15);
      float vv = (c < L) ? sacc[nt][j] : -1e30f;
      sacc[nt][j] = vv;
      mx = fmaxf(mx, vv);
    }
    mx = fmaxf(mx, __shfl_xor(mx, 1, 64));
    mx = fmaxf(mx, __shfl_xor(mx, 2, 64));
    mx = fmaxf(mx, __shfl_xor(mx, 4, 64));
    mx = fmaxf(mx, __shfl_xor(mx, 8, 64));
    float sum = 0.f;
#pragma unroll
    for (int nt = 0; nt < 12; ++nt){
      float pp = exp2f((sacc[nt][j] - mx) * SCL);
      sacc[nt][j] = pp;
      sum += pp;
    }
    sum += __shfl_xor(sum, 1, 64);
    sum += __shfl_xor(sum, 2, 64);
    sum += __shfl_xor(sum, 4, 64);
    sum += __shfl_xor(sum, 8, 64);
    rinv[j] = 1.0f / sum;
  }

  f32x4 oacc[4];
#pragma unroll
  for (int nt = 0; nt < 4; ++nt) oacc[nt] = fz;

#pragma unroll
  for (int kk = 0; kk < 6; ++kk){
#pragma unroll
    for (int ntl = 0; ntl < 2; ++ntl){
      int nt = kk*2 + ntl;
#pragma unroll
      for (int j = 0; j < 4; ++j)
        Pw[w][(lane >> 4)*4 + j][ntl*16 + (lane & 15)] = f2bf(sacc[nt][j]);
    }
    short8 pf = *reinterpret_cast<const short8*>(&Pw[w][lane & 15][(lane >> 4)*8]);
#pragma unroll
    for (int nt4 = 0; nt4 < 4; ++nt4){
      int dcol = nt4*16 + (lane & 15);
      short8 vf = *reinterpret_cast<const short8*>(&Vt[dcol*VSTR + kk*32 + (lane >> 4)*8]);
      oacc[nt4] = __builtin_amdgcn_mfma_f32_16x16x32_bf16(pf, vf, oacc[nt4], 0, 0, 0);
    }
  }

#pragma unroll
  for (int nt4 = 0; nt4 < 4; ++nt4)
#pragma unroll
    for (int j = 0; j < 4; ++j)
      Pw[w][(lane >> 4)*4 + j][nt4*16 + (lane & 15)] = f2bf(oacc[nt4][j] * rinv[j]);

  {
    int r = lane >> 2;
    int gr = row0g + r;
    if (gr < L){
#pragma unroll
      for (int part = 0; part < 2; ++part){
        int c0 = (lane & 3)*16 + part*8;
        short8 vv = *reinterpret_cast<const short8*>(&Pw[w][r][c0]);
        *reinterpret_cast<short8*>(&O[(size_t)(s0 + gr) * E_DIM + h*64 + c0]) = vv;
      }
    }
  }
}

// ---------------- host launch ----------------
extern "C" void kernel_launch(void* const* d_in, const int* in_sizes, int n_in,
                              void* d_out, int out_size, void* d_ws, size_t ws_size,
                              hipStream_t stream)
{
  const float* hs = (const float*)d_in[0];
  const float* Wq = (const float*)d_in[1];
  const float* bq = (const float*)d_in[2];
  const float* Wk = (const float*)d_in[3];
  const float* Wv = (const float*)d_in[4];
  const float* bv = (const float*)d_in[5];
  const float* Wo = (const float*)d_in[6];
  const float* bo = (const float*)d_in[7];
  const int*   cu = (const int*)d_in[8];
  float* out = (float*)d_out;

  unsigned short* p = (unsigned short*)d_ws;
  unsigned short* hsb  = p; p += (size_t)S_TOK * E_DIM;
  unsigned short* wqkv = p; p += (size_t)3 * E_DIM * E_DIM;
  unsigned short* wob  = p; p += (size_t)E_DIM * E_DIM;
  unsigned short* qb   = p; p += (size_t)S_TOK * E_DIM;
  unsigned short* kb   = p; p += (size_t)S_TOK * E_DIM;
  unsigned short* vb   = p; p += (size_t)S_TOK * E_DIM;
  unsigned short* aob  = p; p += (size_t)S_TOK * E_DIM;

  const int nHS4 = S_TOK * E_DIM / 4;
  const int nW4  = E_DIM * E_DIM / 4;
  const int nCvt = nHS4 + 4 * nW4;
  cvt_all<<<(nCvt + 255) / 256, 256, 0, stream>>>(hs, Wq, Wk, Wv, Wo, hsb, wqkv, wob, nHS4, nW4);

  gemm_bt<0><<<(S_TOK/128) * (3*E_DIM/128), 256, 0, stream>>>(
      hsb, wqkv, bq, bv, qb, kb, vb, nullptr, S_TOK, 3*E_DIM, E_DIM);

  attn_kernel<<<H_NUM * NSEG * 3, 256, 0, stream>>>(qb, kb, vb, cu, aob);

  gemm_bt<1><<<(S_TOK/128) * (E_DIM/128), 256, 0, stream>>>(
      aob, wob, bo, nullptr, nullptr, nullptr, nullptr, out, S_TOK, E_DIM, E_DIM);
}

// Round 5
// 111.268 us; speedup vs baseline: 2.0421x; 1.0454x over previous
//
#include <hip/hip_runtime.h>
#include <hip/hip_bf16.h>
#include <stdint.h>

#define S_TOK 3072
#define E_DIM 1280
#define H_NUM 20
#define D_HEAD 64
#define NSEG 16

typedef __attribute__((ext_vector_type(8))) short short8;
typedef __attribute__((ext_vector_type(4))) float f32x4;

__device__ __forceinline__ unsigned short f2bf(float f){
  union { float f; unsigned int i; } u; u.f = f;
  unsigned int r = u.i + 0x7FFFu + ((u.i >> 16) & 1u);
  return (unsigned short)(r >> 16);
}

__device__ __forceinline__ void gload_lds16(const void* g, void* l){
  __builtin_amdgcn_global_load_lds((__attribute__((address_space(1))) void*)(g),
                                   (__attribute__((address_space(3))) void*)(l), 16, 0, 0);
}

// ---------------- all f32 -> bf16 conversions in one launch ----------------
__global__ void cvt_all(const float* __restrict__ hs,
                        const float* __restrict__ w0, const float* __restrict__ w1,
                        const float* __restrict__ w2, const float* __restrict__ w3,
                        unsigned short* __restrict__ hsb,
                        unsigned short* __restrict__ dqkv, unsigned short* __restrict__ dob,
                        int nHS4, int nW4){
  int i = blockIdx.x * blockDim.x + threadIdx.x;
  const float* src;
  unsigned short* dst;
  size_t sj, dj;
  if (i < nHS4){
    src = hs; dst = hsb; sj = i; dj = i;
  } else {
    int t = i - nHS4;
    int w = t / nW4;
    if (w >= 4) return;
    int j = t - w * nW4;
    src = (w == 0) ? w0 : (w == 1) ? w1 : (w == 2) ? w2 : w3;
    sj = j;
    if (w < 3){ dst = dqkv; dj = (size_t)w * nW4 + j; }
    else      { dst = dob;  dj = j; }
  }
  float4 v = reinterpret_cast<const float4*>(src)[sj];
  ushort4 o;
  o.x = f2bf(v.x); o.y = f2bf(v.y); o.z = f2bf(v.z); o.w = f2bf(v.w);
  reinterpret_cast<ushort4*>(dst)[dj] = o;
}

// ---------------- GEMM: C = A[M,K] @ B[N,K]^T  (bf16 in, f32 acc) ----------------
// 128x128 tile, BK=32, TRIPLE-buffered (depth-2 prefetch, counted vmcnt(4)),
// 48 KB LDS -> 3 blocks/CU. Swizzle: phys slot p of row r holds k-chunk
// p ^ ((r>>1)&3)  (rows 0..7 cover all 32 banks once -> 2-way max, free).
// MODE 0: QKV fused (N=3E): LDS-staged coalesced scatter to q/k/v [H][S][D]
// MODE 1: out proj (N=E): f32 out [S][E] + bias
template<int MODE>
__global__ __launch_bounds__(256, 3) void gemm_bt(
    const unsigned short* __restrict__ A,
    const unsigned short* __restrict__ B,
    const float* __restrict__ bias0,
    const float* __restrict__ bias1,
    unsigned short* __restrict__ Oq,
    unsigned short* __restrict__ Ok,
    unsigned short* __restrict__ Ov,
    float* __restrict__ Of,
    int M, int N, int K)
{
  // A bufs: SH + buf*4096 ; B bufs: SH + 12288 + buf*4096 (each 128x32 shorts)
  __shared__ __align__(16) unsigned short SH[24576];

  const int nbn = N >> 7;
  const int bm = blockIdx.x / nbn;
  const int bn = blockIdx.x % nbn;
  const int row0 = bm << 7;
  const int col0 = bn << 7;

  const int tid  = threadIdx.x;
  const int lane = tid & 63;
  const int wrow = ((tid >> 7) & 1) * 64;
  const int wcol = ((tid >> 6) & 1) * 64;

  const f32x4 fz = {0.f, 0.f, 0.f, 0.f};
  f32x4 acc[4][4];
#pragma unroll
  for (int m = 0; m < 4; ++m)
#pragma unroll
    for (int n = 0; n < 4; ++n) acc[m][n] = fz;

  auto stage = [&](int buf, int t){
    const int k0 = t << 5;
    unsigned short* As = SH + buf * 4096;
    unsigned short* Bs = SH + 12288 + buf * 4096;
#pragma unroll
    for (int i = 0; i < 2; ++i){
      int s = i*256 + tid;          // 0..511 16B slots
      int r = s >> 2, p = s & 3;
      int ks = p ^ ((r >> 1) & 3);
      gload_lds16(A + (size_t)(row0 + r)*K + k0 + ks*8, &As[s*8]);
    }
#pragma unroll
    for (int i = 0; i < 2; ++i){
      int s = i*256 + tid;
      int r = s >> 2, p = s & 3;
      int ks = p ^ ((r >> 1) & 3);
      gload_lds16(B + (size_t)(col0 + r)*K + k0 + ks*8, &Bs[s*8]);
    }
  };

  const int nk = K >> 5;                 // 40
  stage(0, 0);
  stage(1, 1);
  int cur = 0;
  for (int t = 0; t < nk; ++t){
    // tile t's 4 loads must be done; tile t+1's 4 may stay in flight
    if (t == nk - 1) asm volatile("s_waitcnt vmcnt(0)" ::: "memory");
    else             asm volatile("s_waitcnt vmcnt(4)" ::: "memory");
    __builtin_amdgcn_s_barrier();
    if (t + 2 < nk){
      int nb = cur + 2; if (nb >= 3) nb -= 3;
      stage(nb, t + 2);
    }
    const unsigned short* As = SH + cur * 4096;
    const unsigned short* Bs = SH + 12288 + cur * 4096;
    short8 af[4], bfr[4];
#pragma unroll
    for (int m = 0; m < 4; ++m){
      int ra = wrow + m*16 + (lane & 15);
      int slot = lane >> 4;
      af[m]  = *reinterpret_cast<const short8*>(&As[ra*32 + ((slot ^ ((ra >> 1) & 3)))*8]);
      int rb = wcol + m*16 + (lane & 15);
      bfr[m] = *reinterpret_cast<const short8*>(&Bs[rb*32 + ((slot ^ ((rb >> 1) & 3)))*8]);
    }
#pragma unroll
    for (int m = 0; m < 4; ++m)
#pragma unroll
      for (int n = 0; n < 4; ++n)
        acc[m][n] = __builtin_amdgcn_mfma_f32_16x16x32_bf16(af[m], bfr[n], acc[m][n], 0, 0, 0);
    ++cur; if (cur >= 3) cur = 0;
  }
  __syncthreads();   // all reads of last buf done before epilogue reuses SH

  if (MODE == 0){
    // LDS-staged coalesced epilogue, two 64-row phases; Cs aliases SH
    unsigned short* Cs = SH;
    const int CSTR = 136;                  // 64 x 136 = 8704 shorts <= 24576
    const int mat = col0 / E_DIM;          // tile-uniform (1280 % 128 == 0)
    const int cc0 = col0 - mat * E_DIM;
    unsigned short* dst = (mat == 0) ? Oq : ((mat == 1) ? Ok : Ov);
#pragma unroll
    for (int ph = 0; ph < 2; ++ph){
      if (wrow == ph*64){
#pragma unroll
        for (int m = 0; m < 4; ++m)
#pragma unroll
          for (int n = 0; n < 4; ++n)
#pragma unroll
            for (int j = 0; j < 4; ++j){
              int r2 = m*16 + (lane >> 4)*4 + j;          // 0..63
              int c  = wcol + n*16 + (lane & 15);         // 0..127
              int cc = cc0 + c;
              float b = (mat == 0) ? bias0[cc] : (mat == 2 ? bias1[cc] : 0.0f);
              Cs[r2*CSTR + c] = f2bf(acc[m][n][j] + b);
            }
      }
      __syncthreads();
      {
        int r = tid >> 2, q = tid & 3;
        int gr = row0 + ph*64 + r;
#pragma unroll
        for (int i = 0; i < 4; ++i){
          int c = q*32 + i*8;
          short8 vv = *reinterpret_cast<const short8*>(&Cs[r*CSTR + c]);
          int cc = cc0 + c;
          int hh = cc >> 6, dd = cc & 63;
          *reinterpret_cast<short8*>(&dst[((size_t)hh * S_TOK + gr) * D_HEAD + dd]) = vv;
        }
      }
      __syncthreads();
    }
  } else {
#pragma unroll
    for (int m = 0; m < 4; ++m)
#pragma unroll
      for (int n = 0; n < 4; ++n)
#pragma unroll
        for (int j = 0; j < 4; ++j){
          int r = row0 + wrow + m*16 + (lane >> 4)*4 + j;
          int c = col0 + wcol + n*16 + (lane & 15);
          Of[(size_t)r * E_DIM + c] = acc[m][n][j] + bias0[c];
        }
  }
}

// ---------------- block-diagonal attention ----------------
// grid = H*NSEG*3 blocks of 256 threads (4 waves x 16 Q-rows = 64 rows/block).
#define VSTR 200
#define PSTR 72
__global__ __launch_bounds__(256, 3) void attn_kernel(
    const unsigned short* __restrict__ Q,
    const unsigned short* __restrict__ Kb,
    const unsigned short* __restrict__ V,
    const int* __restrict__ cu,
    unsigned short* __restrict__ O)
{
  __shared__ __align__(16) unsigned short Vt[64*VSTR];     // [d][k-row]
  __shared__ __align__(16) unsigned short Pw[4][16][PSTR]; // per-wave scratch

  const int bid  = blockIdx.x;
  const int unit = bid / 3;
  const int third= bid - unit*3;
  const int h    = unit >> 4;
  const int seg  = unit & 15;
  const int s0   = cu[seg];
  const int L    = cu[seg + 1] - s0;
  if (L <= 0) return;

  const int tid  = threadIdx.x;
  const int lane = tid & 63;
  const int w    = tid >> 6;
  const int row0g = third*64 + w*16;

  const unsigned short* qh = Q  + (size_t)h * S_TOK * D_HEAD;
  const unsigned short* kh = Kb + (size_t)h * S_TOK * D_HEAD;
  const unsigned short* vh = V  + (size_t)h * S_TOK * D_HEAD;

#pragma unroll
  for (int i = 0; i < 6; ++i){
    int task = i*256 + tid;            // 1536 tasks = 192 rows x 8 d-groups
    int sr   = task % 192;
    int grp  = task / 192;
    int svr  = s0 + (sr < L ? sr : L - 1);
    short8 vv = *reinterpret_cast<const short8*>(vh + (size_t)svr*64 + grp*8);
#pragma unroll
    for (int j = 0; j < 8; ++j) Vt[(grp*8 + j)*VSTR + sr] = (unsigned short)vv[j];
  }

  short8 qf[2];
#pragma unroll
  for (int kk = 0; kk < 2; ++kk){
    int r  = row0g + (lane & 15);
    int sr = s0 + (r < L ? r : L - 1);
    qf[kk] = *reinterpret_cast<const short8*>(qh + (size_t)sr*64 + kk*32 + (lane >> 4)*8);
  }

  __syncthreads();

  const f32x4 fz = {0.f, 0.f, 0.f, 0.f};
  const float SCL = 0.125f * 1.44269504088896f;

  f32x4 sacc[12];
#pragma unroll
  for (int nt = 0; nt < 12; ++nt) sacc[nt] = fz;

#pragma unroll
  for (int nt = 0; nt < 12; ++nt){
    int rb = nt*16 + (lane & 15);
    int sr = s0 + (rb < L ? rb : L - 1);
    const unsigned short* kr = kh + (size_t)sr*64 + (lane >> 4)*8;
    short8 kf0 = *reinterpret_cast<const short8*>(kr);
    short8 kf1 = *reinterpret_cast<const short8*>(kr + 32);
    sacc[nt] = __builtin_amdgcn_mfma_f32_16x16x32_bf16(qf[0], kf0, sacc[nt], 0, 0, 0);
    sacc[nt] = __builtin_amdgcn_mfma_f32_16x16x32_bf16(qf[1], kf1, sacc[nt], 0, 0, 0);
  }

  float rinv[4];
#pragma unroll
  for (int j = 0; j < 4; ++j){
    float mx = -1e30f;
#pragma unroll
    for (int nt = 0; nt < 12; ++nt){
      int c = nt*16 + (lane & 15);
      float vv = (c < L) ? sacc[nt][j] : -1e30f;
      sacc[nt][j] = vv;
      mx = fmaxf(mx, vv);
    }
    mx = fmaxf(mx, __shfl_xor(mx, 1, 64));
    mx = fmaxf(mx, __shfl_xor(mx, 2, 64));
    mx = fmaxf(mx, __shfl_xor(mx, 4, 64));
    mx = fmaxf(mx, __shfl_xor(mx, 8, 64));
    float sum = 0.f;
#pragma unroll
    for (int nt = 0; nt < 12; ++nt){
      float pp = exp2f((sacc[nt][j] - mx) * SCL);
      sacc[nt][j] = pp;
      sum += pp;
    }
    sum += __shfl_xor(sum, 1, 64);
    sum += __shfl_xor(sum, 2, 64);
    sum += __shfl_xor(sum, 4, 64);
    sum += __shfl_xor(sum, 8, 64);
    rinv[j] = 1.0f / sum;
  }

  f32x4 oacc[4];
#pragma unroll
  for (int nt = 0; nt < 4; ++nt) oacc[nt] = fz;

#pragma unroll
  for (int kk = 0; kk < 6; ++kk){
#pragma unroll
    for (int ntl = 0; ntl < 2; ++ntl){
      int nt = kk*2 + ntl;
#pragma unroll
      for (int j = 0; j < 4; ++j)
        Pw[w][(lane >> 4)*4 + j][ntl*16 + (lane & 15)] = f2bf(sacc[nt][j]);
    }
    short8 pf = *reinterpret_cast<const short8*>(&Pw[w][lane & 15][(lane >> 4)*8]);
#pragma unroll
    for (int nt4 = 0; nt4 < 4; ++nt4){
      int dcol = nt4*16 + (lane & 15);
      short8 vf = *reinterpret_cast<const short8*>(&Vt[dcol*VSTR + kk*32 + (lane >> 4)*8]);
      oacc[nt4] = __builtin_amdgcn_mfma_f32_16x16x32_bf16(pf, vf, oacc[nt4], 0, 0, 0);
    }
  }

#pragma unroll
  for (int nt4 = 0; nt4 < 4; ++nt4)
#pragma unroll
    for (int j = 0; j < 4; ++j)
      Pw[w][(lane >> 4)*4 + j][nt4*16 + (lane & 15)] = f2bf(oacc[nt4][j] * rinv[j]);

  {
    int r = lane >> 2;
    int gr = row0g + r;
    if (gr < L){
#pragma unroll
      for (int part = 0; part < 2; ++part){
        int c0 = (lane & 3)*16 + part*8;
        short8 vv = *reinterpret_cast<const short8*>(&Pw[w][r][c0]);
        *reinterpret_cast<short8*>(&O[(size_t)(s0 + gr) * E_DIM + h*64 + c0]) = vv;
      }
    }
  }
}

// ---------------- host launch ----------------
extern "C" void kernel_launch(void* const* d_in, const int* in_sizes, int n_in,
                              void* d_out, int out_size, void* d_ws, size_t ws_size,
                              hipStream_t stream)
{
  const float* hs = (const float*)d_in[0];
  const float* Wq = (const float*)d_in[1];
  const float* bq = (const float*)d_in[2];
  const float* Wk = (const float*)d_in[3];
  const float* Wv = (const float*)d_in[4];
  const float* bv = (const float*)d_in[5];
  const float* Wo = (const float*)d_in[6];
  const float* bo = (const float*)d_in[7];
  const int*   cu = (const int*)d_in[8];
  float* out = (float*)d_out;

  unsigned short* p = (unsigned short*)d_ws;
  unsigned short* hsb  = p; p += (size_t)S_TOK * E_DIM;
  unsigned short* wqkv = p; p += (size_t)3 * E_DIM * E_DIM;
  unsigned short* wob  = p; p += (size_t)E_DIM * E_DIM;
  unsigned short* qb   = p; p += (size_t)S_TOK * E_DIM;
  unsigned short* kb   = p; p += (size_t)S_TOK * E_DIM;
  unsigned short* vb   = p; p += (size_t)S_TOK * E_DIM;
  unsigned short* aob  = p; p += (size_t)S_TOK * E_DIM;

  const int nHS4 = S_TOK * E_DIM / 4;
  const int nW4  = E_DIM * E_DIM / 4;
  const int nCvt = nHS4 + 4 * nW4;
  cvt_all<<<(nCvt + 255) / 256, 256, 0, stream>>>(hs, Wq, Wk, Wv, Wo, hsb, wqkv, wob, nHS4, nW4);

  gemm_bt<0><<<(S_TOK/128) * (3*E_DIM/128), 256, 0, stream>>>(
      hsb, wqkv, bq, bv, qb, kb, vb, nullptr, S_TOK, 3*E_DIM, E_DIM);

  attn_kernel<<<H_NUM * NSEG * 3, 256, 0, stream>>>(qb, kb, vb, cu, aob);

  gemm_bt<1><<<(S_TOK/128) * (E_DIM/128), 256, 0, stream>>>(
      aob, wob, bo, nullptr, nullptr, nullptr, nullptr, out, S_TOK, E_DIM, E_DIM);
}